// Round 16
// baseline (86.626 us; speedup 1.0000x reference)
//
#include <hip/hip_runtime.h>
#include <math.h>

// DegradedBicycleRollout: b=512, l=64, h=80, state=12.
// R16: h-PARALLEL scan decomposition. R5-R15 proved the serial chain wave is
// an invariant ~4.6 steps/us wall regardless of instruction/trans count or
// structure. Bypass: the recurrence is associative once s'=max(s2,1e-3)
// (R15-validated): speed = max-plus scan of f(s)=max(s+A,B); psi/px/py =
// prefix sums; everything else pointwise. 8 threads/rollout x 10 steps,
// width-8 shuffle scans, no LDS, no barriers, 4096 waves (16/CU).
// Stores: 480B contiguous per thread, thread-contiguous -> fill-kernel regime.

#define DT_F 0.1f
#define INV2PI 0.15915494309189535f

__device__ __forceinline__ float fast_rcp(float x) { return __builtin_amdgcn_rcpf(x); }

__global__ __launch_bounds__(256) void degraded_bicycle_rollout_kernel(
    const float* __restrict__ x0,        // [512,12]
    const float* __restrict__ controls,  // [512,64,80,3]
    const float* __restrict__ deg,       // [512,5]
    float* __restrict__ out)             // [512,64,81,12]
{
    const int tid = blockIdx.x * 256 + threadIdx.x;  // 0..262143
    const int rid = tid >> 3;            // rollout id = b*64 + l
    const int j   = tid & 7;             // segment: steps 10j..10j+9
    const int b   = rid >> 6;            // uniform per block (32 rollouts/block)

    // --- degradation params (block-uniform -> scalar regs) ---
    const float steer_scale    = fmaxf(deg[b * 5 + 0], 0.05f);
    const float brake_scale    = fmaxf(deg[b * 5 + 1], 0.05f);
    const float throttle_scale = fmaxf(deg[b * 5 + 2], 0.05f);
    const float friction       = fmaxf(deg[b * 5 + 4], 0.1f);
    const float neg_brake_lim = -7.5f * friction;
    const float yaw_num = friction * 9.81f;
    const float inv_wb = 1.0f / 2.8f;

    const float px0  = x0[b * 12 + 0];
    const float py0  = x0[b * 12 + 1];
    const float psi0 = x0[b * 12 + 2];
    const float vx0  = x0[b * 12 + 3];
    const float vy0  = x0[b * 12 + 4];
    const float s0 = __builtin_amdgcn_sqrtf(fmaf(vx0, vx0, fmaf(vy0, vy0, 1e-6f)));

    // --- load this segment's 30 control floats (8B-aligned float2s) ---
    float u[30];
    {
        const float2* cp = reinterpret_cast<const float2*>(
            controls + (size_t)rid * 240 + j * 30);
        #pragma unroll
        for (int i = 0; i < 15; ++i) {
            const float2 v = cp[i];
            u[2 * i] = v.x; u[2 * i + 1] = v.y;
        }
    }

    // --- pointwise control transforms (combined-rcp, polys; R15 math) ---
    float tan_d[10], beta[10], dl[10], fb[10], fx[10], a[10];
    #pragma unroll
    for (int t = 0; t < 10; ++t) {
        const float e2 = __expf(2.0f * u[3 * t]);
        const float eb = __expf(-u[3 * t + 1]);
        const float ec = __expf(-u[3 * t + 2]);
        const float ad = e2 + 1.0f, bd = 1.0f + eb, cd = 1.0f + ec;
        const float bc = bd * cd;
        const float invP = fast_rcp(ad * bc);    // one rcp for all 3 denoms
        const float delta = steer_scale * ((e2 - 1.0f) * (invP * bc));
        const float fbv = brake_scale    * (invP * (ad * cd));
        const float fxv = throttle_scale * (invP * (ad * bd));
        const float dc = fminf(fmaxf(delta, -0.75f), 0.75f);
        const float x2 = dc * dc;                // tan poly, |dc|<=0.75
        float p = 0.0035916f;
        p = fmaf(p, x2, 0.0088632f);
        p = fmaf(p, x2, 0.0218695f);
        p = fmaf(p, x2, 0.0539683f);
        p = fmaf(p, x2, 0.1333333f);
        p = fmaf(p, x2, 0.3333333f);
        const float td = fmaf(p * x2, dc, dc);
        const float z = 0.45f * td;              // atan poly, |z|<=0.42
        const float z2 = z * z;
        float q = 1.0f / 9.0f;
        q = fmaf(q, z2, -1.0f / 7.0f);
        q = fmaf(q, z2, 1.0f / 5.0f);
        q = fmaf(q, z2, -1.0f / 3.0f);
        q = fmaf(q, z2, 1.0f);
        const float bt = z * q;                  // |beta|<=0.3973 (clip dead)
        const float acc = fminf(fmaxf(2.8f * fxv - 6.5f * fbv, neg_brake_lim), 3.0f);
        tan_d[t] = td; beta[t] = bt; dl[t] = delta;
        fb[t] = fbv; fx[t] = fxv; a[t] = acc * DT_F;
    }

    // --- speed: max-plus composite scan. f_t(s)=max(s+a_t, 1e-3) ---
    float A = 0.0f, B = -1e30f;                  // thread composite F(s)=max(s+A,B)
    #pragma unroll
    for (int t = 0; t < 10; ++t) { B = fmaxf(B + a[t], 1e-3f); A += a[t]; }
    #pragma unroll
    for (int off = 1; off < 8; off <<= 1) {      // inclusive width-8 scan
        const float Ap = __shfl_up(A, off, 8);
        const float Bp = __shfl_up(B, off, 8);
        const float nB = fmaxf(Bp + A, B);       // earlier X=(Ap,Bp) applied first
        const float nA = A + Ap;
        if (j >= off) { A = nA; B = nB; }
    }
    const float Aex = __shfl_up(A, 1, 8);        // exclusive
    const float Bex = __shfl_up(B, 1, 8);
    float s = (j == 0) ? s0 : fmaxf(s0 + Aex, Bex);  // incoming speed state

    // --- sweep 1: s2, yaw_rate, segment dpsi ---
    float s2[10], yr[10];
    float dpsi = 0.0f;
    #pragma unroll
    for (int t = 0; t < 10; ++t) {
        const float s2t = fmaxf(s + a[t], 0.0f);
        const float raw = s2t * inv_wb * tan_d[t];
        const float lim = fmaxf(yaw_num * fast_rcp(fmaxf(s2t, 2.0f)), 0.15f);
        const float y = fminf(fmaxf(raw, -1.0f), 1.0f) * lim;
        s2[t] = s2t; yr[t] = y; dpsi += y;
        s = fmaxf(s2t, 1e-3f);                   // ~= sqrt(s2^2+1e-6), err<=5e-4
    }
    dpsi *= DT_F;

    // --- psi prefix ---
    float ps = dpsi;
    #pragma unroll
    for (int off = 1; off < 8; off <<= 1) {
        const float pp = __shfl_up(ps, off, 8);
        if (j >= off) ps += pp;
    }
    const float ps_ex = __shfl_up(ps, 1, 8);
    const float psi_in = psi0 + ((j == 0) ? 0.0f : ps_ex);

    // --- pointwise vx, vy ---
    float vx[10], vy[10];
    {
        float pr = psi_in;
        #pragma unroll
        for (int t = 0; t < 10; ++t) {
            pr = fmaf(yr[t], DT_F, pr);
            const float ang = (pr + beta[t]) * INV2PI;
            vx[t] = s2[t] * __builtin_amdgcn_cosf(ang);
            vy[t] = s2[t] * __builtin_amdgcn_sinf(ang);
        }
    }

    // --- px, py prefixes ---
    float svx = 0.0f, svy = 0.0f;
    #pragma unroll
    for (int t = 0; t < 10; ++t) { svx += vx[t]; svy += vy[t]; }
    svx *= DT_F; svy *= DT_F;
    float sx = svx, sy = svy;
    #pragma unroll
    for (int off = 1; off < 8; off <<= 1) {
        const float qx = __shfl_up(sx, off, 8);
        const float qy = __shfl_up(sy, off, 8);
        if (j >= off) { sx += qx; sy += qy; }
    }
    const float sx_ex = __shfl_up(sx, 1, 8);
    const float sy_ex = __shfl_up(sy, 1, 8);
    float px = px0 + ((j == 0) ? 0.0f : sx_ex);
    float py = py0 + ((j == 0) ? 0.0f : sy_ex);

    // --- previous-velocity boundary (for ax, ay) ---
    const float lvx = __shfl_up(vx[9], 1, 8);
    const float lvy = __shfl_up(vy[9], 1, 8);
    float pvx = (j == 0) ? vx0 : lvx;
    float pvy = (j == 0) ? vy0 : lvy;

    // --- final sweep + fully-coalesced stores (480B/thread, contiguous) ---
    float4* op = reinterpret_cast<float4*>(out + (size_t)rid * 972 + 12 + j * 120);
    float psir = psi_in;
    #pragma unroll
    for (int t = 0; t < 10; ++t) {
        psir = fmaf(yr[t], DT_F, psir);
        px = fmaf(vx[t], DT_F, px);
        py = fmaf(vy[t], DT_F, py);
        const float ax = (vx[t] - pvx) * 10.0f;
        const float ay = (vy[t] - pvy) * 10.0f;
        op[3 * t + 0] = make_float4(px, py, psir, vx[t]);
        op[3 * t + 1] = make_float4(vy[t], yr[t], ax, ay);
        op[3 * t + 2] = make_float4(beta[t], dl[t], fb[t], fx[t]);
        pvx = vx[t]; pvy = vy[t];
    }

    // --- h=0 row: full x0 broadcast (thread j==0 of each rollout) ---
    if (j == 0) {
        float4* o0 = reinterpret_cast<float4*>(out + (size_t)rid * 972);
        o0[0] = make_float4(px0, py0, psi0, vx0);
        o0[1] = make_float4(vy0, x0[b * 12 + 5], x0[b * 12 + 6], x0[b * 12 + 7]);
        o0[2] = make_float4(x0[b * 12 + 8], x0[b * 12 + 9], x0[b * 12 + 10], x0[b * 12 + 11]);
    }
}

extern "C" void kernel_launch(void* const* d_in, const int* in_sizes, int n_in,
                              void* d_out, int out_size, void* d_ws, size_t ws_size,
                              hipStream_t stream) {
    (void)in_sizes; (void)n_in; (void)d_ws; (void)ws_size; (void)out_size;
    const float* x0       = (const float*)d_in[0];
    const float* controls = (const float*)d_in[1];
    const float* deg      = (const float*)d_in[2];
    float* out            = (float*)d_out;

    // 512*64 rollouts x 8 threads = 262144 threads = 1024 blocks x 256
    dim3 grid(1024), block(256);
    hipLaunchKernelGGL(degraded_bicycle_rollout_kernel, grid, block, 0, stream,
                       x0, controls, deg, out);
}